// Round 15
// baseline (259.018 us; speedup 1.0000x reference)
//
#include <hip/hip_runtime.h>
#include <hip/hip_bf16.h>
#include <hip/hip_fp16.h>

constexpr int HDIM = 8;
constexpr int EDIM = 8;

typedef _Float16 half8 __attribute__((ext_vector_type(8)));
typedef _Float16 h2f16 __attribute__((ext_vector_type(2)));
typedef float f32x4 __attribute__((ext_vector_type(4)));
union H8U { uint4 u; half8 h; };
union H2U { unsigned u; h2f16 h; };

__device__ __forceinline__ unsigned pack2h(float a, float b) {
  __half2 h = __floats2half2_rn(a, b);
  union { __half2 h2; unsigned u; } u;
  u.h2 = h;
  return u.u;
}

__device__ __forceinline__ h2f16 u2h(unsigned v) {
  H2U u; u.u = v; return u.h;
}

// h = x @ node_W + node_b -> f16 h, fused with layer-0 BN stats + deg zeroing.
__global__ __launch_bounds__(256) void init_h_stats_kernel(
    const float* __restrict__ x, const float* __restrict__ W, const float* __restrict__ b,
    unsigned short* __restrict__ h, float* __restrict__ sums, int* __restrict__ deg, int n) {
  __shared__ float reds[256], redq[256];
  int tid = threadIdx.x, lane = tid & 63;
  int gtid = blockIdx.x * 256 + tid;
  for (int i = gtid; i < n; i += 512 * 256) deg[i] = 0;
  float wc[HDIM];
#pragma unroll
  for (int k = 0; k < HDIM; ++k) wc[k] = W[k * 64 + lane];
  float bc = b[lane];
  float s = 0.f, q = 0.f;
  int total = n * 64;
  for (int gid = gtid; gid < total; gid += 512 * 256) {
    int row = gid >> 6;
    const float* xr = x + (size_t)row * HDIM;
    float acc = bc;
#pragma unroll
    for (int k = 0; k < HDIM; ++k) acc = fmaf(xr[k], wc[k], acc);
    h[gid] = __half_as_ushort(__float2half(acc));
    s += acc;
    q = fmaf(acc, acc, q);
  }
  reds[tid] = s; redq[tid] = q;
  __syncthreads();
  if (tid < 64) {
    float S = reds[tid] + reds[64 + tid] + reds[128 + tid] + reds[192 + tid];
    float Q = redq[tid] + redq[64 + tid] + redq[128 + tid] + redq[192 + tid];
    int slot = blockIdx.x & 7;
    atomicAdd(&sums[slot * 128 + tid], S);
    atomicAdd(&sums[slot * 128 + 64 + tid], Q);
  }
}

__global__ void deg_kernel(const int* __restrict__ dst, int* __restrict__ deg,
                           int* __restrict__ idxw, int E) {
  int e = blockIdx.x * 256 + threadIdx.x;
  if (e < E) idxw[e] = atomicAdd(&deg[dst[e]], 1);
}

__global__ __launch_bounds__(256) void scan_part_kernel(const int* __restrict__ deg,
                                                        int* __restrict__ partials, int n) {
  __shared__ int sh[256];
  int tid = threadIdx.x, idx = blockIdx.x * 256 + tid;
  int v = (idx < n) ? deg[idx] : 0;
  sh[tid] = v;
  __syncthreads();
  for (int o = 128; o > 0; o >>= 1) {
    if (tid < o) sh[tid] += sh[tid + o];
    __syncthreads();
  }
  if (tid == 0) partials[blockIdx.x] = sh[0];
}

__global__ __launch_bounds__(1024) void scan_top_kernel(int* __restrict__ partials, int nb) {
  __shared__ int sh[1024];
  int tid = threadIdx.x;
  int v = (tid < nb) ? partials[tid] : 0;
  sh[tid] = v;
  __syncthreads();
  for (int o = 1; o < 1024; o <<= 1) {
    int a = (tid >= o) ? sh[tid - o] : 0;
    __syncthreads();
    sh[tid] += a;
    __syncthreads();
  }
  if (tid < nb) partials[tid] = sh[tid] - v;  // exclusive
}

__global__ __launch_bounds__(256) void scan_fill_kernel(
    const int* __restrict__ deg, const int* __restrict__ partials,
    int* __restrict__ rowstart, int n, int total) {
  __shared__ int sh[256];
  int tid = threadIdx.x, idx = blockIdx.x * 256 + tid;
  int v = (idx < n) ? deg[idx] : 0;
  sh[tid] = v;
  __syncthreads();
  for (int o = 1; o < 256; o <<= 1) {
    int a = (tid >= o) ? sh[tid - o] : 0;
    __syncthreads();
    sh[tid] += a;
    __syncthreads();
  }
  if (idx < n) rowstart[idx] = partials[blockIdx.x] + sh[tid] - v;
  if (blockIdx.x == 0 && tid == 0) rowstart[n] = total;
}

// scatter ONE 32B record per edge: {f16 ea[8] (16B), src (4B), pad}. No atomics.
__global__ void fill_kernel(const int* __restrict__ src, const int* __restrict__ dst,
                            const int* __restrict__ idxw, const int* __restrict__ rowstart,
                            const float* __restrict__ edge_attr, char* __restrict__ recs, int E) {
  int e = blockIdx.x * 256 + threadIdx.x;
  if (e >= E) return;
  int d = dst[e];
  int slot = rowstart[d] + idxw[e];
  const float4* ap = (const float4*)(edge_attr + (size_t)e * EDIM);
  float4 a = ap[0], c = ap[1];
  uint4 rv;
  rv.x = pack2h(a.x, a.y);
  rv.y = pack2h(a.z, a.w);
  rv.z = pack2h(c.x, c.y);
  rv.w = pack2h(c.z, c.w);
  char* rb = recs + (size_t)slot * 32;
  *(uint4*)rb = rv;
  *(int*)(rb + 16) = src[e];
}

// Fused BN+ReLU + message + softmax-agg on f16 h. 1 wave/node, lane=channel.
// Projection via v_dot2_f32_f16 (4 ops); eps folded out of the loop (softmax
// shift-invariance: agg = num/den + eps); exp2f with prescaled temperature.
__global__ __launch_bounds__(256) void aggregate_kernel(
    const unsigned short* __restrict__ h, const float* __restrict__ sums,
    const float* __restrict__ bn_g, const float* __restrict__ bn_b,
    const int* __restrict__ rowstart, const char* __restrict__ recs,
    const float* __restrict__ edge_W, const float* __restrict__ edge_b,
    const float* __restrict__ t, unsigned short* __restrict__ out, int n, float invN) {
  int lane = threadIdx.x & 63;
  int node = blockIdx.x * 4 + (threadIdx.x >> 6);
  if (node >= n) return;
  float ssum = 0.f, qsum = 0.f;
#pragma unroll
  for (int k = 0; k < 8; ++k) {
    ssum += sums[k * 128 + lane];
    qsum += sums[k * 128 + 64 + lane];
  }
  float mu = ssum * invN;
  float var = qsum * invN - mu * mu;
  float aa = rsqrtf(var + 1e-5f) * bn_g[lane];
  float cc = bn_b[lane] - mu * aa;
  h2f16 wc2[4];
#pragma unroll
  for (int k = 0; k < 4; ++k) {
    H2U u;
    u.u = pack2h(edge_W[(2 * k) * 64 + lane], edge_W[(2 * k + 1) * 64 + lane]);
    wc2[k] = u.h;
  }
  float eb = edge_b[lane];
  float tt2 = t[0] * 1.44269504088896f;  // exp(x*t) = exp2(x*t*log2e)
  int s0 = __builtin_amdgcn_readfirstlane(rowstart[node]);
  int s1 = __builtin_amdgcn_readfirstlane(rowstart[node + 1]);
  float hd = fmaxf(fmaf(__half2float(__ushort_as_half(h[(size_t)node * 64 + lane])), aa, cc), 0.f);
  float den = 0.f, num = 0.f;
#define EDGE_STEP(HU, RV)                                                      \
  {                                                                            \
    float ev = __builtin_amdgcn_fdot2(u2h(RV.x), wc2[0], eb, false);           \
    ev = __builtin_amdgcn_fdot2(u2h(RV.y), wc2[1], ev, false);                 \
    ev = __builtin_amdgcn_fdot2(u2h(RV.z), wc2[2], ev, false);                 \
    ev = __builtin_amdgcn_fdot2(u2h(RV.w), wc2[3], ev, false);                 \
    float hnv = fmaxf(fmaf(__half2float(__ushort_as_half(HU)), aa, cc), 0.f);  \
    float m = fmaxf(hnv + ev, 0.f);                                            \
    float p = exp2f(m * tt2);                                                  \
    den += p;                                                                  \
    num = fmaf(p, m, num);                                                     \
  }
  int j = s0;
  for (; j + 8 <= s1; j += 8) {
    const char* rb = recs + (size_t)j * 32;
    uint4 r0 = *(const uint4*)(rb);
    uint4 r1 = *(const uint4*)(rb + 32);
    uint4 r2 = *(const uint4*)(rb + 64);
    uint4 r3 = *(const uint4*)(rb + 96);
    uint4 r4 = *(const uint4*)(rb + 128);
    uint4 r5 = *(const uint4*)(rb + 160);
    uint4 r6 = *(const uint4*)(rb + 192);
    uint4 r7 = *(const uint4*)(rb + 224);
    int i0 = *(const int*)(rb + 16);
    int i1 = *(const int*)(rb + 48);
    int i2 = *(const int*)(rb + 80);
    int i3 = *(const int*)(rb + 112);
    int i4 = *(const int*)(rb + 144);
    int i5 = *(const int*)(rb + 176);
    int i6 = *(const int*)(rb + 208);
    int i7 = *(const int*)(rb + 240);
    unsigned short u0 = h[(size_t)i0 * 64 + lane];
    unsigned short u1 = h[(size_t)i1 * 64 + lane];
    unsigned short u2 = h[(size_t)i2 * 64 + lane];
    unsigned short u3 = h[(size_t)i3 * 64 + lane];
    unsigned short u4 = h[(size_t)i4 * 64 + lane];
    unsigned short u5 = h[(size_t)i5 * 64 + lane];
    unsigned short u6 = h[(size_t)i6 * 64 + lane];
    unsigned short u7 = h[(size_t)i7 * 64 + lane];
    EDGE_STEP(u0, r0)
    EDGE_STEP(u1, r1)
    EDGE_STEP(u2, r2)
    EDGE_STEP(u3, r3)
    EDGE_STEP(u4, r4)
    EDGE_STEP(u5, r5)
    EDGE_STEP(u6, r6)
    EDGE_STEP(u7, r7)
  }
  for (; j + 4 <= s1; j += 4) {
    const char* rb = recs + (size_t)j * 32;
    uint4 r0 = *(const uint4*)(rb);
    uint4 r1 = *(const uint4*)(rb + 32);
    uint4 r2 = *(const uint4*)(rb + 64);
    uint4 r3 = *(const uint4*)(rb + 96);
    int i0 = *(const int*)(rb + 16);
    int i1 = *(const int*)(rb + 48);
    int i2 = *(const int*)(rb + 80);
    int i3 = *(const int*)(rb + 112);
    unsigned short u0 = h[(size_t)i0 * 64 + lane];
    unsigned short u1 = h[(size_t)i1 * 64 + lane];
    unsigned short u2 = h[(size_t)i2 * 64 + lane];
    unsigned short u3 = h[(size_t)i3 * 64 + lane];
    EDGE_STEP(u0, r0)
    EDGE_STEP(u1, r1)
    EDGE_STEP(u2, r2)
    EDGE_STEP(u3, r3)
  }
  for (; j < s1; ++j) {
    const char* rb = recs + (size_t)j * 32;
    uint4 r0 = *(const uint4*)(rb);
    int i0 = *(const int*)(rb + 16);
    unsigned short u0 = h[(size_t)i0 * 64 + lane];
    EDGE_STEP(u0, r0)
  }
#undef EDGE_STEP
  float res = num / fmaxf(den, 1e-16f) + 1e-7f + hd;
  out[(size_t)node * 64 + lane] = __half_as_ushort(__float2half(res));
}

// MFMA MLP on f16 streams (unchanged from R14).
__global__ __launch_bounds__(256) void mlp_mfma_kernel(
    const unsigned short* __restrict__ outv, const unsigned short* __restrict__ h_in,
    const float* __restrict__ W1, const float* __restrict__ b1,
    const float* __restrict__ lng, const float* __restrict__ lnb,
    const float* __restrict__ W2, const float* __restrict__ b2,
    unsigned short* __restrict__ hout16, float* __restrict__ hout32,
    float* __restrict__ nextsums, int n) {
  __shared__ uint4 lds[2560];  // 40KB
  const int tid = threadIdx.x;
  const int wv = tid >> 6, l = tid & 63;
  const int n0 = blockIdx.x * 64;
  uint4* XA = lds;
  uint4* WB = lds + 512;
  uint4* ZF = lds + 1536;
#pragma unroll
  for (int i = 0; i < 2; ++i) {
    int c = tid + i * 256;
    int node = c >> 3, k8 = c & 7;
    int nd = n0 + node;
    uint4 u;
    if (nd < n) {
      u = *(const uint4*)(outv + (size_t)nd * 64 + k8 * 8);
    } else {
      u = make_uint4(0, 0, 0, 0);
    }
    int mt = node >> 4, kt = k8 >> 2;
    int lanep = ((k8 & 3) << 4) | (node & 15);
    XA[(mt * 2 + kt) * 64 + lanep] = u;
  }
#pragma unroll
  for (int i = 0; i < 4; ++i) {
    int c = tid + i * 256;
    int fid = c >> 6, lp = c & 63;
    int nt = fid >> 1, kt = fid & 1;
    int ncol = (nt << 4) | (lp & 15);
    int k0 = kt * 32 + (lp >> 4) * 8;
    half8 hv;
#pragma unroll
    for (int j = 0; j < 8; ++j) hv[j] = (_Float16)W1[(size_t)(k0 + j) * 128 + ncol];
    H8U u; u.h = hv;
    WB[fid * 64 + lp] = u.u;
  }
  __syncthreads();
  f32x4 cfr[8];
#pragma unroll
  for (int nt = 0; nt < 8; ++nt) cfr[nt] = (f32x4){0.f, 0.f, 0.f, 0.f};
  {
    H8U a0, a1;
    a0.u = XA[(wv * 2 + 0) * 64 + l];
    a1.u = XA[(wv * 2 + 1) * 64 + l];
#pragma unroll
    for (int nt = 0; nt < 8; ++nt) {
      H8U b0, b1u;
      b0.u = WB[(nt * 2 + 0) * 64 + l];
      b1u.u = WB[(nt * 2 + 1) * 64 + l];
      cfr[nt] = __builtin_amdgcn_mfma_f32_16x16x32_f16(a0.h, b0.h, cfr[nt], 0, 0, 0);
      cfr[nt] = __builtin_amdgcn_mfma_f32_16x16x32_f16(a1.h, b1u.h, cfr[nt], 0, 0, 0);
    }
  }
  int col = l & 15;
  float s4[4] = {0.f, 0.f, 0.f, 0.f}, q4[4] = {0.f, 0.f, 0.f, 0.f};
#pragma unroll
  for (int nt = 0; nt < 8; ++nt) {
    float bb = b1[nt * 16 + col];
#pragma unroll
    for (int r = 0; r < 4; ++r) {
      float v = cfr[nt][r] + bb;
      cfr[nt][r] = v;
      s4[r] += v;
      q4[r] = fmaf(v, v, q4[r]);
    }
  }
#pragma unroll
  for (int off = 1; off < 16; off <<= 1) {
#pragma unroll
    for (int r = 0; r < 4; ++r) {
      s4[r] += __shfl_xor(s4[r], off, 64);
      q4[r] += __shfl_xor(q4[r], off, 64);
    }
  }
  float mu4[4], rs4[4];
#pragma unroll
  for (int r = 0; r < 4; ++r) {
    float mu = s4[r] * (1.f / 128.f);
    float var = q4[r] * (1.f / 128.f) - mu * mu;
    mu4[r] = mu;
    rs4[r] = rsqrtf(var + 1e-5f);
  }
  {
    unsigned short* ZB = (unsigned short*)ZF;
#pragma unroll
    for (int nt = 0; nt < 8; ++nt) {
      int ch = nt * 16 + col;
      int kt2 = ch >> 5, kl = ch & 31;
      float g = lng[ch], bb = lnb[ch];
#pragma unroll
      for (int r = 0; r < 4; ++r) {
        int row = (l >> 4) * 4 + r;
        float zv = fmaxf((cfr[nt][r] - mu4[r]) * rs4[r] * g + bb, 0.f);
        int lanep = ((kl >> 3) << 4) | row;
        ZB[((wv * 4 + kt2) * 64 + lanep) * 8 + (kl & 7)] = __half_as_ushort(__float2half(zv));
      }
    }
  }
  __syncthreads();
#pragma unroll
  for (int i = 0; i < 4; ++i) {
    int c = tid + i * 256;
    int fid = c >> 6, lp = c & 63;
    int nt2 = fid >> 2, kt2 = fid & 3;
    int ncol = (nt2 << 4) | (lp & 15);
    int k0 = kt2 * 32 + (lp >> 4) * 8;
    half8 hv;
#pragma unroll
    for (int j = 0; j < 8; ++j) hv[j] = (_Float16)W2[(size_t)(k0 + j) * 64 + ncol];
    H8U u; u.h = hv;
    WB[fid * 64 + lp] = u.u;
  }
  __syncthreads();
  f32x4 dfr[4];
#pragma unroll
  for (int nt2 = 0; nt2 < 4; ++nt2) dfr[nt2] = (f32x4){0.f, 0.f, 0.f, 0.f};
  {
    H8U za[4];
#pragma unroll
    for (int kt2 = 0; kt2 < 4; ++kt2) za[kt2].u = ZF[(wv * 4 + kt2) * 64 + l];
#pragma unroll
    for (int nt2 = 0; nt2 < 4; ++nt2) {
#pragma unroll
      for (int kt2 = 0; kt2 < 4; ++kt2) {
        H8U bu;
        bu.u = WB[(nt2 * 4 + kt2) * 64 + l];
        dfr[nt2] = __builtin_amdgcn_mfma_f32_16x16x32_f16(za[kt2].h, bu.h, dfr[nt2], 0, 0, 0);
      }
    }
  }
  float ssum[4] = {0.f, 0.f, 0.f, 0.f}, qsum[4] = {0.f, 0.f, 0.f, 0.f};
#pragma unroll
  for (int nt2 = 0; nt2 < 4; ++nt2) {
    int ch2 = nt2 * 16 + col;
    float bb = b2[ch2];
#pragma unroll
    for (int r = 0; r < 4; ++r) {
      int nd = n0 + wv * 16 + (l >> 4) * 4 + r;
      if (nd < n) {
        float hv = __half2float(__ushort_as_half(h_in[(size_t)nd * 64 + ch2]));
        float v = hv + dfr[nt2][r] + bb;
        if (hout32 != nullptr) {
          hout32[(size_t)nd * 64 + ch2] = v;
        } else {
          hout16[(size_t)nd * 64 + ch2] = __half_as_ushort(__float2half(v));
        }
        ssum[nt2] += v;
        qsum[nt2] = fmaf(v, v, qsum[nt2]);
      }
    }
  }
  if (nextsums != nullptr) {
#pragma unroll
    for (int nt2 = 0; nt2 < 4; ++nt2) {
      ssum[nt2] += __shfl_xor(ssum[nt2], 16, 64);
      ssum[nt2] += __shfl_xor(ssum[nt2], 32, 64);
      qsum[nt2] += __shfl_xor(qsum[nt2], 16, 64);
      qsum[nt2] += __shfl_xor(qsum[nt2], 32, 64);
    }
    float* SS = (float*)(ZF + wv * 256);
    if (l < 16) {
#pragma unroll
      for (int nt2 = 0; nt2 < 4; ++nt2) {
        SS[nt2 * 16 + l] = ssum[nt2];
        SS[64 + nt2 * 16 + l] = qsum[nt2];
      }
    }
    __syncthreads();
    if (tid < 64) {
      float S = 0.f, Q = 0.f;
#pragma unroll
      for (int w = 0; w < 4; ++w) {
        const float* P = (const float*)(ZF + w * 256);
        S += P[tid];
        Q += P[64 + tid];
      }
      int slot = blockIdx.x & 7;
      atomicAdd(&nextsums[slot * 128 + tid], S);
      atomicAdd(&nextsums[slot * 128 + 64 + tid], Q);
    }
  }
}

extern "C" void kernel_launch(void* const* d_in, const int* in_sizes, int n_in,
                              void* d_out, int out_size, void* d_ws, size_t ws_size,
                              hipStream_t stream) {
  const float* x = (const float*)d_in[0];
  const int* edge_index = (const int*)d_in[1];
  const float* edge_attr = (const float*)d_in[2];
  const float* node_W = (const float*)d_in[3];
  const float* node_b = (const float*)d_in[4];
  const float* edge_W = (const float*)d_in[5];
  const float* edge_b = (const float*)d_in[6];
  const float* bn_g = (const float*)d_in[7];
  const float* bn_b = (const float*)d_in[8];
  const float* t = (const float*)d_in[9];
  const float* W1 = (const float*)d_in[10];
  const float* b1 = (const float*)d_in[11];
  const float* ln_g = (const float*)d_in[12];
  const float* ln_b = (const float*)d_in[13];
  const float* W2 = (const float*)d_in[14];
  const float* b2 = (const float*)d_in[15];

  int N = in_sizes[0] / HDIM;
  int E = in_sizes[1] / 2;
  const int* srcp = edge_index;
  const int* dstp = edge_index + E;

  char* ws = (char*)d_ws;
  size_t off = 0;
  auto alloc = [&](size_t bytes) {
    char* p = ws + off;
    off = (off + bytes + 255) & ~(size_t)255;
    return p;
  };
  int* deg = (int*)alloc((size_t)N * 4);
  int* rowstart = (int*)alloc(((size_t)N + 1) * 4);
  int* idxw = (int*)alloc((size_t)E * 4);
  int* partials = (int*)alloc(1024 * 4);
  float* bnsums = (float*)alloc(3 * 1024 * 4);
  char* recs = (char*)alloc((size_t)E * 32);
  unsigned short* h = (unsigned short*)alloc((size_t)N * 64 * 2);
  unsigned short* outv = (unsigned short*)alloc((size_t)N * 64 * 2);
  (void)ws_size; (void)n_in; (void)out_size;

  int nb = (N + 255) / 256;
  hipMemsetAsync(bnsums, 0, 3 * 1024 * 4, stream);
  init_h_stats_kernel<<<512, 256, 0, stream>>>(x, node_W, node_b, h, bnsums, deg, N);
  deg_kernel<<<(E + 255) / 256, 256, 0, stream>>>(dstp, deg, idxw, E);
  scan_part_kernel<<<nb, 256, 0, stream>>>(deg, partials, N);
  scan_top_kernel<<<1, 1024, 0, stream>>>(partials, nb);
  scan_fill_kernel<<<nb, 256, 0, stream>>>(deg, partials, rowstart, N, E);
  fill_kernel<<<(E + 255) / 256, 256, 0, stream>>>(srcp, dstp, idxw, rowstart, edge_attr, recs, E);

  float invN = 1.0f / (float)N;
  int mlp_blocks = (N + 63) / 64;
  for (int l = 0; l < 3; ++l) {
    aggregate_kernel<<<(N + 3) / 4, 256, 0, stream>>>(
        h, bnsums + l * 1024, bn_g + l * 64, bn_b + l * 64, rowstart, recs,
        edge_W, edge_b, t + l, outv, N, invN);
    unsigned short* h16 = (l == 2) ? nullptr : h;
    float* h32 = (l == 2) ? (float*)d_out : nullptr;
    float* nxt = (l == 2) ? nullptr : (bnsums + (l + 1) * 1024);
    mlp_mfma_kernel<<<mlp_blocks, 256, 0, stream>>>(outv, h, W1 + (size_t)l * 8192, b1 + l * 128,
                                                    ln_g + l * 128, ln_b + l * 128,
                                                    W2 + (size_t)l * 8192, b2 + l * 64,
                                                    h16, h32, nxt, N);
  }
}

// Round 16
// 252.332 us; speedup vs baseline: 1.0265x; 1.0265x over previous
//
#include <hip/hip_runtime.h>
#include <hip/hip_bf16.h>
#include <hip/hip_fp16.h>

constexpr int HDIM = 8;
constexpr int EDIM = 8;

typedef _Float16 half8 __attribute__((ext_vector_type(8)));
typedef _Float16 h2f16 __attribute__((ext_vector_type(2)));
typedef float f32x4 __attribute__((ext_vector_type(4)));
union H8U { uint4 u; half8 h; };
union H2U { unsigned u; h2f16 h; };

__device__ __forceinline__ unsigned pack2h(float a, float b) {
  __half2 h = __floats2half2_rn(a, b);
  union { __half2 h2; unsigned u; } u;
  u.h2 = h;
  return u.u;
}

__device__ __forceinline__ h2f16 u2h(unsigned v) {
  H2U u; u.u = v; return u.h;
}

// h = x @ node_W + node_b -> f16 h, fused with layer-0 BN stats + deg zeroing.
__global__ __launch_bounds__(256) void init_h_stats_kernel(
    const float* __restrict__ x, const float* __restrict__ W, const float* __restrict__ b,
    unsigned short* __restrict__ h, float* __restrict__ sums, int* __restrict__ deg, int n) {
  __shared__ float reds[256], redq[256];
  int tid = threadIdx.x, lane = tid & 63;
  int gtid = blockIdx.x * 256 + tid;
  for (int i = gtid; i < n; i += 512 * 256) deg[i] = 0;
  float wc[HDIM];
#pragma unroll
  for (int k = 0; k < HDIM; ++k) wc[k] = W[k * 64 + lane];
  float bc = b[lane];
  float s = 0.f, q = 0.f;
  int total = n * 64;
  for (int gid = gtid; gid < total; gid += 512 * 256) {
    int row = gid >> 6;
    const float* xr = x + (size_t)row * HDIM;
    float acc = bc;
#pragma unroll
    for (int k = 0; k < HDIM; ++k) acc = fmaf(xr[k], wc[k], acc);
    h[gid] = __half_as_ushort(__float2half(acc));
    s += acc;
    q = fmaf(acc, acc, q);
  }
  reds[tid] = s; redq[tid] = q;
  __syncthreads();
  if (tid < 64) {
    float S = reds[tid] + reds[64 + tid] + reds[128 + tid] + reds[192 + tid];
    float Q = redq[tid] + redq[64 + tid] + redq[128 + tid] + redq[192 + tid];
    int slot = blockIdx.x & 7;
    atomicAdd(&sums[slot * 128 + tid], S);
    atomicAdd(&sums[slot * 128 + 64 + tid], Q);
  }
}

__global__ void deg_kernel(const int* __restrict__ dst, int* __restrict__ deg,
                           int* __restrict__ idxw, int E) {
  int e = blockIdx.x * 256 + threadIdx.x;
  if (e < E) idxw[e] = atomicAdd(&deg[dst[e]], 1);
}

__global__ __launch_bounds__(256) void scan_part_kernel(const int* __restrict__ deg,
                                                        int* __restrict__ partials, int n) {
  __shared__ int sh[256];
  int tid = threadIdx.x, idx = blockIdx.x * 256 + tid;
  int v = (idx < n) ? deg[idx] : 0;
  sh[tid] = v;
  __syncthreads();
  for (int o = 128; o > 0; o >>= 1) {
    if (tid < o) sh[tid] += sh[tid + o];
    __syncthreads();
  }
  if (tid == 0) partials[blockIdx.x] = sh[0];
}

__global__ __launch_bounds__(1024) void scan_top_kernel(int* __restrict__ partials, int nb) {
  __shared__ int sh[1024];
  int tid = threadIdx.x;
  int v = (tid < nb) ? partials[tid] : 0;
  sh[tid] = v;
  __syncthreads();
  for (int o = 1; o < 1024; o <<= 1) {
    int a = (tid >= o) ? sh[tid - o] : 0;
    __syncthreads();
    sh[tid] += a;
    __syncthreads();
  }
  if (tid < nb) partials[tid] = sh[tid] - v;  // exclusive
}

__global__ __launch_bounds__(256) void scan_fill_kernel(
    const int* __restrict__ deg, const int* __restrict__ partials,
    int* __restrict__ rowstart, int n, int total) {
  __shared__ int sh[256];
  int tid = threadIdx.x, idx = blockIdx.x * 256 + tid;
  int v = (idx < n) ? deg[idx] : 0;
  sh[tid] = v;
  __syncthreads();
  for (int o = 1; o < 256; o <<= 1) {
    int a = (tid >= o) ? sh[tid - o] : 0;
    __syncthreads();
    sh[tid] += a;
    __syncthreads();
  }
  if (idx < n) rowstart[idx] = partials[blockIdx.x] + sh[tid] - v;
  if (blockIdx.x == 0 && tid == 0) rowstart[n] = total;
}

// scatter ONE 32B record per edge: {f16 ea[8] (16B), src (4B), pad}. No atomics.
__global__ void fill_kernel(const int* __restrict__ src, const int* __restrict__ dst,
                            const int* __restrict__ idxw, const int* __restrict__ rowstart,
                            const float* __restrict__ edge_attr, char* __restrict__ recs, int E) {
  int e = blockIdx.x * 256 + threadIdx.x;
  if (e >= E) return;
  int d = dst[e];
  int slot = rowstart[d] + idxw[e];
  const float4* ap = (const float4*)(edge_attr + (size_t)e * EDIM);
  float4 a = ap[0], c = ap[1];
  uint4 rv;
  rv.x = pack2h(a.x, a.y);
  rv.y = pack2h(a.z, a.w);
  rv.z = pack2h(c.x, c.y);
  rv.w = pack2h(c.z, c.w);
  char* rb = recs + (size_t)slot * 32;
  *(uint4*)rb = rv;
  *(int*)(rb + 16) = src[e];
}

// Fused BN+ReLU + message + softmax-agg on f16 h. 1 wave/node, lane=channel.
// 32-bit addressing: gather byte-offset = i*128 + lane*2 (u24-mul range),
// record offsets = 32-bit j*32 off a uniform base. Dual den/num accumulators.
__global__ __launch_bounds__(256) void aggregate_kernel(
    const unsigned short* __restrict__ h, const float* __restrict__ sums,
    const float* __restrict__ bn_g, const float* __restrict__ bn_b,
    const int* __restrict__ rowstart, const char* __restrict__ recs,
    const float* __restrict__ edge_W, const float* __restrict__ edge_b,
    const float* __restrict__ t, unsigned short* __restrict__ out, int n, float invN) {
  int lane = threadIdx.x & 63;
  int node = blockIdx.x * 4 + (threadIdx.x >> 6);
  if (node >= n) return;
  float ssum = 0.f, qsum = 0.f;
#pragma unroll
  for (int k = 0; k < 8; ++k) {
    ssum += sums[k * 128 + lane];
    qsum += sums[k * 128 + 64 + lane];
  }
  float mu = ssum * invN;
  float var = qsum * invN - mu * mu;
  float aa = rsqrtf(var + 1e-5f) * bn_g[lane];
  float cc = bn_b[lane] - mu * aa;
  h2f16 wc2[4];
#pragma unroll
  for (int k = 0; k < 4; ++k) {
    H2U u;
    u.u = pack2h(edge_W[(2 * k) * 64 + lane], edge_W[(2 * k + 1) * 64 + lane]);
    wc2[k] = u.h;
  }
  float eb = edge_b[lane];
  float tt2 = t[0] * 1.44269504088896f;
  int s0 = __builtin_amdgcn_readfirstlane(rowstart[node]);
  int s1 = __builtin_amdgcn_readfirstlane(rowstart[node + 1]);
  const char* hB = (const char*)h;       // gather base; offsets 32-bit
  const unsigned lane2 = (unsigned)lane * 2u;
  float hd;
  {
    unsigned o = (unsigned)node * 128u + lane2;
    hd = fmaxf(fmaf(__half2float(__ushort_as_half(*(const unsigned short*)(hB + o))), aa, cc), 0.f);
  }
  float den0 = 0.f, num0 = 0.f, den1 = 0.f, num1 = 0.f;
#define EDGE_STEP(HU, RV, DEN, NUM)                                            \
  {                                                                            \
    float ev = __builtin_amdgcn_fdot2(u2h(RV.x), wc2[0], eb, false);           \
    ev = __builtin_amdgcn_fdot2(u2h(RV.y), wc2[1], ev, false);                 \
    ev = __builtin_amdgcn_fdot2(u2h(RV.z), wc2[2], ev, false);                 \
    ev = __builtin_amdgcn_fdot2(u2h(RV.w), wc2[3], ev, false);                 \
    float hnv = fmaxf(fmaf(__half2float(__ushort_as_half(HU)), aa, cc), 0.f);  \
    float m = fmaxf(hnv + ev, 0.f);                                            \
    float p = exp2f(m * tt2);                                                  \
    DEN += p;                                                                  \
    NUM = fmaf(p, m, NUM);                                                     \
  }
#define GATHER(I) (*(const unsigned short*)(hB + ((unsigned)(I) * 128u + lane2)))
  int j = s0;
  for (; j + 8 <= s1; j += 8) {
    unsigned jb = (unsigned)j * 32u;
    uint4 r0 = *(const uint4*)(recs + jb);
    uint4 r1 = *(const uint4*)(recs + jb + 32);
    uint4 r2 = *(const uint4*)(recs + jb + 64);
    uint4 r3 = *(const uint4*)(recs + jb + 96);
    uint4 r4 = *(const uint4*)(recs + jb + 128);
    uint4 r5 = *(const uint4*)(recs + jb + 160);
    uint4 r6 = *(const uint4*)(recs + jb + 192);
    uint4 r7 = *(const uint4*)(recs + jb + 224);
    int i0 = *(const int*)(recs + jb + 16);
    int i1 = *(const int*)(recs + jb + 48);
    int i2 = *(const int*)(recs + jb + 80);
    int i3 = *(const int*)(recs + jb + 112);
    int i4 = *(const int*)(recs + jb + 144);
    int i5 = *(const int*)(recs + jb + 176);
    int i6 = *(const int*)(recs + jb + 208);
    int i7 = *(const int*)(recs + jb + 240);
    unsigned short u0 = GATHER(i0);
    unsigned short u1 = GATHER(i1);
    unsigned short u2 = GATHER(i2);
    unsigned short u3 = GATHER(i3);
    unsigned short u4 = GATHER(i4);
    unsigned short u5 = GATHER(i5);
    unsigned short u6 = GATHER(i6);
    unsigned short u7 = GATHER(i7);
    EDGE_STEP(u0, r0, den0, num0)
    EDGE_STEP(u1, r1, den1, num1)
    EDGE_STEP(u2, r2, den0, num0)
    EDGE_STEP(u3, r3, den1, num1)
    EDGE_STEP(u4, r4, den0, num0)
    EDGE_STEP(u5, r5, den1, num1)
    EDGE_STEP(u6, r6, den0, num0)
    EDGE_STEP(u7, r7, den1, num1)
  }
  for (; j + 4 <= s1; j += 4) {
    unsigned jb = (unsigned)j * 32u;
    uint4 r0 = *(const uint4*)(recs + jb);
    uint4 r1 = *(const uint4*)(recs + jb + 32);
    uint4 r2 = *(const uint4*)(recs + jb + 64);
    uint4 r3 = *(const uint4*)(recs + jb + 96);
    int i0 = *(const int*)(recs + jb + 16);
    int i1 = *(const int*)(recs + jb + 48);
    int i2 = *(const int*)(recs + jb + 80);
    int i3 = *(const int*)(recs + jb + 112);
    unsigned short u0 = GATHER(i0);
    unsigned short u1 = GATHER(i1);
    unsigned short u2 = GATHER(i2);
    unsigned short u3 = GATHER(i3);
    EDGE_STEP(u0, r0, den0, num0)
    EDGE_STEP(u1, r1, den1, num1)
    EDGE_STEP(u2, r2, den0, num0)
    EDGE_STEP(u3, r3, den1, num1)
  }
  for (; j < s1; ++j) {
    unsigned jb = (unsigned)j * 32u;
    uint4 r0 = *(const uint4*)(recs + jb);
    int i0 = *(const int*)(recs + jb + 16);
    unsigned short u0 = GATHER(i0);
    EDGE_STEP(u0, r0, den0, num0)
  }
#undef GATHER
#undef EDGE_STEP
  float den = den0 + den1, num = num0 + num1;
  float res = num / fmaxf(den, 1e-16f) + 1e-7f + hd;
  {
    unsigned o = (unsigned)node * 128u + lane2;
    *(unsigned short*)((char*)out + o) = __half_as_ushort(__float2half(res));
  }
}

// MFMA MLP on f16 streams (unchanged from R14).
__global__ __launch_bounds__(256) void mlp_mfma_kernel(
    const unsigned short* __restrict__ outv, const unsigned short* __restrict__ h_in,
    const float* __restrict__ W1, const float* __restrict__ b1,
    const float* __restrict__ lng, const float* __restrict__ lnb,
    const float* __restrict__ W2, const float* __restrict__ b2,
    unsigned short* __restrict__ hout16, float* __restrict__ hout32,
    float* __restrict__ nextsums, int n) {
  __shared__ uint4 lds[2560];  // 40KB
  const int tid = threadIdx.x;
  const int wv = tid >> 6, l = tid & 63;
  const int n0 = blockIdx.x * 64;
  uint4* XA = lds;
  uint4* WB = lds + 512;
  uint4* ZF = lds + 1536;
#pragma unroll
  for (int i = 0; i < 2; ++i) {
    int c = tid + i * 256;
    int node = c >> 3, k8 = c & 7;
    int nd = n0 + node;
    uint4 u;
    if (nd < n) {
      u = *(const uint4*)(outv + (size_t)nd * 64 + k8 * 8);
    } else {
      u = make_uint4(0, 0, 0, 0);
    }
    int mt = node >> 4, kt = k8 >> 2;
    int lanep = ((k8 & 3) << 4) | (node & 15);
    XA[(mt * 2 + kt) * 64 + lanep] = u;
  }
#pragma unroll
  for (int i = 0; i < 4; ++i) {
    int c = tid + i * 256;
    int fid = c >> 6, lp = c & 63;
    int nt = fid >> 1, kt = fid & 1;
    int ncol = (nt << 4) | (lp & 15);
    int k0 = kt * 32 + (lp >> 4) * 8;
    half8 hv;
#pragma unroll
    for (int j = 0; j < 8; ++j) hv[j] = (_Float16)W1[(size_t)(k0 + j) * 128 + ncol];
    H8U u; u.h = hv;
    WB[fid * 64 + lp] = u.u;
  }
  __syncthreads();
  f32x4 cfr[8];
#pragma unroll
  for (int nt = 0; nt < 8; ++nt) cfr[nt] = (f32x4){0.f, 0.f, 0.f, 0.f};
  {
    H8U a0, a1;
    a0.u = XA[(wv * 2 + 0) * 64 + l];
    a1.u = XA[(wv * 2 + 1) * 64 + l];
#pragma unroll
    for (int nt = 0; nt < 8; ++nt) {
      H8U b0, b1u;
      b0.u = WB[(nt * 2 + 0) * 64 + l];
      b1u.u = WB[(nt * 2 + 1) * 64 + l];
      cfr[nt] = __builtin_amdgcn_mfma_f32_16x16x32_f16(a0.h, b0.h, cfr[nt], 0, 0, 0);
      cfr[nt] = __builtin_amdgcn_mfma_f32_16x16x32_f16(a1.h, b1u.h, cfr[nt], 0, 0, 0);
    }
  }
  int col = l & 15;
  float s4[4] = {0.f, 0.f, 0.f, 0.f}, q4[4] = {0.f, 0.f, 0.f, 0.f};
#pragma unroll
  for (int nt = 0; nt < 8; ++nt) {
    float bb = b1[nt * 16 + col];
#pragma unroll
    for (int r = 0; r < 4; ++r) {
      float v = cfr[nt][r] + bb;
      cfr[nt][r] = v;
      s4[r] += v;
      q4[r] = fmaf(v, v, q4[r]);
    }
  }
#pragma unroll
  for (int off = 1; off < 16; off <<= 1) {
#pragma unroll
    for (int r = 0; r < 4; ++r) {
      s4[r] += __shfl_xor(s4[r], off, 64);
      q4[r] += __shfl_xor(q4[r], off, 64);
    }
  }
  float mu4[4], rs4[4];
#pragma unroll
  for (int r = 0; r < 4; ++r) {
    float mu = s4[r] * (1.f / 128.f);
    float var = q4[r] * (1.f / 128.f) - mu * mu;
    mu4[r] = mu;
    rs4[r] = rsqrtf(var + 1e-5f);
  }
  {
    unsigned short* ZB = (unsigned short*)ZF;
#pragma unroll
    for (int nt = 0; nt < 8; ++nt) {
      int ch = nt * 16 + col;
      int kt2 = ch >> 5, kl = ch & 31;
      float g = lng[ch], bb = lnb[ch];
#pragma unroll
      for (int r = 0; r < 4; ++r) {
        int row = (l >> 4) * 4 + r;
        float zv = fmaxf((cfr[nt][r] - mu4[r]) * rs4[r] * g + bb, 0.f);
        int lanep = ((kl >> 3) << 4) | row;
        ZB[((wv * 4 + kt2) * 64 + lanep) * 8 + (kl & 7)] = __half_as_ushort(__float2half(zv));
      }
    }
  }
  __syncthreads();
#pragma unroll
  for (int i = 0; i < 4; ++i) {
    int c = tid + i * 256;
    int fid = c >> 6, lp = c & 63;
    int nt2 = fid >> 2, kt2 = fid & 3;
    int ncol = (nt2 << 4) | (lp & 15);
    int k0 = kt2 * 32 + (lp >> 4) * 8;
    half8 hv;
#pragma unroll
    for (int j = 0; j < 8; ++j) hv[j] = (_Float16)W2[(size_t)(k0 + j) * 64 + ncol];
    H8U u; u.h = hv;
    WB[fid * 64 + lp] = u.u;
  }
  __syncthreads();
  f32x4 dfr[4];
#pragma unroll
  for (int nt2 = 0; nt2 < 4; ++nt2) dfr[nt2] = (f32x4){0.f, 0.f, 0.f, 0.f};
  {
    H8U za[4];
#pragma unroll
    for (int kt2 = 0; kt2 < 4; ++kt2) za[kt2].u = ZF[(wv * 4 + kt2) * 64 + l];
#pragma unroll
    for (int nt2 = 0; nt2 < 4; ++nt2) {
#pragma unroll
      for (int kt2 = 0; kt2 < 4; ++kt2) {
        H8U bu;
        bu.u = WB[(nt2 * 4 + kt2) * 64 + l];
        dfr[nt2] = __builtin_amdgcn_mfma_f32_16x16x32_f16(za[kt2].h, bu.h, dfr[nt2], 0, 0, 0);
      }
    }
  }
  float ssum[4] = {0.f, 0.f, 0.f, 0.f}, qsum[4] = {0.f, 0.f, 0.f, 0.f};
#pragma unroll
  for (int nt2 = 0; nt2 < 4; ++nt2) {
    int ch2 = nt2 * 16 + col;
    float bb = b2[ch2];
#pragma unroll
    for (int r = 0; r < 4; ++r) {
      int nd = n0 + wv * 16 + (l >> 4) * 4 + r;
      if (nd < n) {
        float hv = __half2float(__ushort_as_half(h_in[(size_t)nd * 64 + ch2]));
        float v = hv + dfr[nt2][r] + bb;
        if (hout32 != nullptr) {
          hout32[(size_t)nd * 64 + ch2] = v;
        } else {
          hout16[(size_t)nd * 64 + ch2] = __half_as_ushort(__float2half(v));
        }
        ssum[nt2] += v;
        qsum[nt2] = fmaf(v, v, qsum[nt2]);
      }
    }
  }
  if (nextsums != nullptr) {
#pragma unroll
    for (int nt2 = 0; nt2 < 4; ++nt2) {
      ssum[nt2] += __shfl_xor(ssum[nt2], 16, 64);
      ssum[nt2] += __shfl_xor(ssum[nt2], 32, 64);
      qsum[nt2] += __shfl_xor(qsum[nt2], 16, 64);
      qsum[nt2] += __shfl_xor(qsum[nt2], 32, 64);
    }
    float* SS = (float*)(ZF + wv * 256);
    if (l < 16) {
#pragma unroll
      for (int nt2 = 0; nt2 < 4; ++nt2) {
        SS[nt2 * 16 + l] = ssum[nt2];
        SS[64 + nt2 * 16 + l] = qsum[nt2];
      }
    }
    __syncthreads();
    if (tid < 64) {
      float S = 0.f, Q = 0.f;
#pragma unroll
      for (int w = 0; w < 4; ++w) {
        const float* P = (const float*)(ZF + w * 256);
        S += P[tid];
        Q += P[64 + tid];
      }
      int slot = blockIdx.x & 7;
      atomicAdd(&nextsums[slot * 128 + tid], S);
      atomicAdd(&nextsums[slot * 128 + 64 + tid], Q);
    }
  }
}

extern "C" void kernel_launch(void* const* d_in, const int* in_sizes, int n_in,
                              void* d_out, int out_size, void* d_ws, size_t ws_size,
                              hipStream_t stream) {
  const float* x = (const float*)d_in[0];
  const int* edge_index = (const int*)d_in[1];
  const float* edge_attr = (const float*)d_in[2];
  const float* node_W = (const float*)d_in[3];
  const float* node_b = (const float*)d_in[4];
  const float* edge_W = (const float*)d_in[5];
  const float* edge_b = (const float*)d_in[6];
  const float* bn_g = (const float*)d_in[7];
  const float* bn_b = (const float*)d_in[8];
  const float* t = (const float*)d_in[9];
  const float* W1 = (const float*)d_in[10];
  const float* b1 = (const float*)d_in[11];
  const float* ln_g = (const float*)d_in[12];
  const float* ln_b = (const float*)d_in[13];
  const float* W2 = (const float*)d_in[14];
  const float* b2 = (const float*)d_in[15];

  int N = in_sizes[0] / HDIM;
  int E = in_sizes[1] / 2;
  const int* srcp = edge_index;
  const int* dstp = edge_index + E;

  char* ws = (char*)d_ws;
  size_t off = 0;
  auto alloc = [&](size_t bytes) {
    char* p = ws + off;
    off = (off + bytes + 255) & ~(size_t)255;
    return p;
  };
  int* deg = (int*)alloc((size_t)N * 4);
  int* rowstart = (int*)alloc(((size_t)N + 1) * 4);
  int* idxw = (int*)alloc((size_t)E * 4);
  int* partials = (int*)alloc(1024 * 4);
  float* bnsums = (float*)alloc(3 * 1024 * 4);
  char* recs = (char*)alloc((size_t)E * 32);
  unsigned short* h = (unsigned short*)alloc((size_t)N * 64 * 2);
  unsigned short* outv = (unsigned short*)alloc((size_t)N * 64 * 2);
  (void)ws_size; (void)n_in; (void)out_size;

  int nb = (N + 255) / 256;
  hipMemsetAsync(bnsums, 0, 3 * 1024 * 4, stream);
  init_h_stats_kernel<<<512, 256, 0, stream>>>(x, node_W, node_b, h, bnsums, deg, N);
  deg_kernel<<<(E + 255) / 256, 256, 0, stream>>>(dstp, deg, idxw, E);
  scan_part_kernel<<<nb, 256, 0, stream>>>(deg, partials, N);
  scan_top_kernel<<<1, 1024, 0, stream>>>(partials, nb);
  scan_fill_kernel<<<nb, 256, 0, stream>>>(deg, partials, rowstart, N, E);
  fill_kernel<<<(E + 255) / 256, 256, 0, stream>>>(srcp, dstp, idxw, rowstart, edge_attr, recs, E);

  float invN = 1.0f / (float)N;
  int mlp_blocks = (N + 63) / 64;
  for (int l = 0; l < 3; ++l) {
    aggregate_kernel<<<(N + 3) / 4, 256, 0, stream>>>(
        h, bnsums + l * 1024, bn_g + l * 64, bn_b + l * 64, rowstart, recs,
        edge_W, edge_b, t + l, outv, N, invN);
    unsigned short* h16 = (l == 2) ? nullptr : h;
    float* h32 = (l == 2) ? (float*)d_out : nullptr;
    float* nxt = (l == 2) ? nullptr : (bnsums + (l + 1) * 1024);
    mlp_mfma_kernel<<<mlp_blocks, 256, 0, stream>>>(outv, h, W1 + (size_t)l * 8192, b1 + l * 128,
                                                    ln_g + l * 128, ln_b + l * 128,
                                                    W2 + (size_t)l * 8192, b2 + l * 64,
                                                    h16, h32, nxt, N);
  }
}

// Round 17
// 243.902 us; speedup vs baseline: 1.0620x; 1.0346x over previous
//
#include <hip/hip_runtime.h>
#include <hip/hip_bf16.h>
#include <hip/hip_fp16.h>

constexpr int HDIM = 8;
constexpr int EDIM = 8;

typedef _Float16 half8 __attribute__((ext_vector_type(8)));
typedef _Float16 h2f16 __attribute__((ext_vector_type(2)));
typedef float f32x4 __attribute__((ext_vector_type(4)));
typedef unsigned u32x4 __attribute__((ext_vector_type(4)));
union H8U { uint4 u; half8 h; };
union H2U { unsigned u; h2f16 h; };

__device__ __forceinline__ unsigned pack2h(float a, float b) {
  __half2 h = __floats2half2_rn(a, b);
  union { __half2 h2; unsigned u; } u;
  u.h2 = h;
  return u.u;
}

__device__ __forceinline__ h2f16 u2h(unsigned v) {
  H2U u; u.u = v; return u.h;
}

// h = x @ node_W + node_b -> f16, + layer-0 BN stats + edge histogram (deg pre-zeroed
// by host memset, so the histogram can live here instead of its own dispatch).
__global__ __launch_bounds__(256) void init_h_stats_kernel(
    const float* __restrict__ x, const float* __restrict__ W, const float* __restrict__ b,
    unsigned short* __restrict__ h, float* __restrict__ sums,
    const int* __restrict__ dst, int* __restrict__ idxw, int* __restrict__ deg,
    int n, int E) {
  __shared__ float reds[256], redq[256];
  int tid = threadIdx.x, lane = tid & 63;
  int gtid = blockIdx.x * 256 + tid;
  for (int e = gtid; e < E; e += 512 * 256) idxw[e] = atomicAdd(&deg[dst[e]], 1);
  float wc[HDIM];
#pragma unroll
  for (int k = 0; k < HDIM; ++k) wc[k] = W[k * 64 + lane];
  float bc = b[lane];
  float s = 0.f, q = 0.f;
  int total = n * 64;
  for (int gid = gtid; gid < total; gid += 512 * 256) {
    int row = gid >> 6;
    const float* xr = x + (size_t)row * HDIM;
    float acc = bc;
#pragma unroll
    for (int k = 0; k < HDIM; ++k) acc = fmaf(xr[k], wc[k], acc);
    h[gid] = __half_as_ushort(__float2half(acc));
    s += acc;
    q = fmaf(acc, acc, q);
  }
  reds[tid] = s; redq[tid] = q;
  __syncthreads();
  if (tid < 64) {
    float S = reds[tid] + reds[64 + tid] + reds[128 + tid] + reds[192 + tid];
    float Q = redq[tid] + redq[64 + tid] + redq[128 + tid] + redq[192 + tid];
    int slot = blockIdx.x & 7;
    atomicAdd(&sums[slot * 128 + tid], S);
    atomicAdd(&sums[slot * 128 + 64 + tid], Q);
  }
}

__global__ __launch_bounds__(256) void scan_part_kernel(const int* __restrict__ deg,
                                                        int* __restrict__ partials, int n) {
  __shared__ int sh[256];
  int tid = threadIdx.x, idx = blockIdx.x * 256 + tid;
  int v = (idx < n) ? deg[idx] : 0;
  sh[tid] = v;
  __syncthreads();
  for (int o = 128; o > 0; o >>= 1) {
    if (tid < o) sh[tid] += sh[tid + o];
    __syncthreads();
  }
  if (tid == 0) partials[blockIdx.x] = sh[0];
}

// Every block redundantly top-scans the <=256 partials in LDS (784B, L2-hot),
// then scans its own 256-chunk -> rowstart. Replaces scan_top + scan_fill.
__global__ __launch_bounds__(256) void scan_fill_kernel(
    const int* __restrict__ deg, const int* __restrict__ partials,
    int* __restrict__ rowstart, int n, int total, int nb) {
  __shared__ int tp[256];
  __shared__ int sh[256];
  int tid = threadIdx.x, idx = blockIdx.x * 256 + tid;
  int pv = (tid < nb) ? partials[tid] : 0;
  tp[tid] = pv;
  int v = (idx < n) ? deg[idx] : 0;
  sh[tid] = v;
  __syncthreads();
  for (int o = 1; o < 256; o <<= 1) {
    int a1 = (tid >= o) ? tp[tid - o] : 0;
    int a2 = (tid >= o) ? sh[tid - o] : 0;
    __syncthreads();
    tp[tid] += a1;
    sh[tid] += a2;
    __syncthreads();
  }
  int base = (blockIdx.x == 0) ? 0 : tp[blockIdx.x - 1];  // exclusive block prefix
  if (idx < n) rowstart[idx] = base + sh[tid] - v;
  if (blockIdx.x == 0 && tid == 0) rowstart[n] = total;
}

// scatter ONE 32B record per edge: {f16 ea[8] (16B), src (4B), pad}. No atomics.
__global__ void fill_kernel(const int* __restrict__ src, const int* __restrict__ dst,
                            const int* __restrict__ idxw, const int* __restrict__ rowstart,
                            const float* __restrict__ edge_attr, char* __restrict__ recs, int E) {
  int e = blockIdx.x * 256 + threadIdx.x;
  if (e >= E) return;
  int d = dst[e];
  int slot = rowstart[d] + idxw[e];
  const float4* ap = (const float4*)(edge_attr + (size_t)e * EDIM);
  float4 a = ap[0], c = ap[1];
  uint4 rv;
  rv.x = pack2h(a.x, a.y);
  rv.y = pack2h(a.z, a.w);
  rv.z = pack2h(c.x, c.y);
  rv.w = pack2h(c.z, c.w);
  char* rb = recs + (size_t)slot * 32;
  *(uint4*)rb = rv;
  *(int*)(rb + 16) = src[e];
}

// One node's softmax-aggregation (edge loop). Records read non-temporally
// (stream-once) so the f16 h gather target stays L2-resident.
__device__ __forceinline__ float agg_one(
    int node, unsigned lane2, const char* __restrict__ hB,
    const int* __restrict__ rowstart, const char* __restrict__ recs,
    const h2f16* wc2, float eb, float tt2, float aa, float cc) {
  int s0 = __builtin_amdgcn_readfirstlane(rowstart[node]);
  int s1 = __builtin_amdgcn_readfirstlane(rowstart[node + 1]);
  float hd;
  {
    unsigned o = (unsigned)node * 128u + lane2;
    hd = fmaxf(fmaf(__half2float(__ushort_as_half(*(const unsigned short*)(hB + o))), aa, cc), 0.f);
  }
  float den0 = 0.f, num0 = 0.f, den1 = 0.f, num1 = 0.f;
#define EDGE_STEP(HU, RV, DEN, NUM)                                            \
  {                                                                            \
    float ev = __builtin_amdgcn_fdot2(u2h(RV.x), wc2[0], eb, false);           \
    ev = __builtin_amdgcn_fdot2(u2h(RV.y), wc2[1], ev, false);                 \
    ev = __builtin_amdgcn_fdot2(u2h(RV.z), wc2[2], ev, false);                 \
    ev = __builtin_amdgcn_fdot2(u2h(RV.w), wc2[3], ev, false);                 \
    float hnv = fmaxf(fmaf(__half2float(__ushort_as_half(HU)), aa, cc), 0.f);  \
    float m = fmaxf(hnv + ev, 0.f);                                            \
    float p = exp2f(m * tt2);                                                  \
    DEN += p;                                                                  \
    NUM = fmaf(p, m, NUM);                                                     \
  }
#define GATHER(I) (*(const unsigned short*)(hB + ((unsigned)(I) * 128u + lane2)))
#define NT4(OFF) __builtin_nontemporal_load((const u32x4*)(recs + jb + (OFF)))
#define NTI(OFF) __builtin_nontemporal_load((const int*)(recs + jb + (OFF)))
  int j = s0;
  for (; j + 8 <= s1; j += 8) {
    unsigned jb = (unsigned)j * 32u;
    u32x4 r0 = NT4(0);
    u32x4 r1 = NT4(32);
    u32x4 r2 = NT4(64);
    u32x4 r3 = NT4(96);
    u32x4 r4 = NT4(128);
    u32x4 r5 = NT4(160);
    u32x4 r6 = NT4(192);
    u32x4 r7 = NT4(224);
    int i0 = NTI(16);
    int i1 = NTI(48);
    int i2 = NTI(80);
    int i3 = NTI(112);
    int i4 = NTI(144);
    int i5 = NTI(176);
    int i6 = NTI(208);
    int i7 = NTI(240);
    unsigned short u0 = GATHER(i0);
    unsigned short u1 = GATHER(i1);
    unsigned short u2 = GATHER(i2);
    unsigned short u3 = GATHER(i3);
    unsigned short u4 = GATHER(i4);
    unsigned short u5 = GATHER(i5);
    unsigned short u6 = GATHER(i6);
    unsigned short u7 = GATHER(i7);
    EDGE_STEP(u0, r0, den0, num0)
    EDGE_STEP(u1, r1, den1, num1)
    EDGE_STEP(u2, r2, den0, num0)
    EDGE_STEP(u3, r3, den1, num1)
    EDGE_STEP(u4, r4, den0, num0)
    EDGE_STEP(u5, r5, den1, num1)
    EDGE_STEP(u6, r6, den0, num0)
    EDGE_STEP(u7, r7, den1, num1)
  }
  for (; j + 4 <= s1; j += 4) {
    unsigned jb = (unsigned)j * 32u;
    u32x4 r0 = NT4(0);
    u32x4 r1 = NT4(32);
    u32x4 r2 = NT4(64);
    u32x4 r3 = NT4(96);
    int i0 = NTI(16);
    int i1 = NTI(48);
    int i2 = NTI(80);
    int i3 = NTI(112);
    unsigned short u0 = GATHER(i0);
    unsigned short u1 = GATHER(i1);
    unsigned short u2 = GATHER(i2);
    unsigned short u3 = GATHER(i3);
    EDGE_STEP(u0, r0, den0, num0)
    EDGE_STEP(u1, r1, den1, num1)
    EDGE_STEP(u2, r2, den0, num0)
    EDGE_STEP(u3, r3, den1, num1)
  }
  for (; j < s1; ++j) {
    unsigned jb = (unsigned)j * 32u;
    u32x4 r0 = NT4(0);
    int i0 = NTI(16);
    unsigned short u0 = GATHER(i0);
    EDGE_STEP(u0, r0, den0, num0)
  }
#undef NT4
#undef NTI
#undef GATHER
#undef EDGE_STEP
  float den = den0 + den1, num = num0 + num1;
  return num / fmaxf(den, 1e-16f) + 1e-7f + hd;
}

// Fused BN+ReLU + message + softmax-agg. 2 nodes per wave (setup amortized 2x),
// lane = channel.
__global__ __launch_bounds__(256) void aggregate_kernel(
    const unsigned short* __restrict__ h, const float* __restrict__ sums,
    const float* __restrict__ bn_g, const float* __restrict__ bn_b,
    const int* __restrict__ rowstart, const char* __restrict__ recs,
    const float* __restrict__ edge_W, const float* __restrict__ edge_b,
    const float* __restrict__ t, unsigned short* __restrict__ out, int n, float invN) {
  int lane = threadIdx.x & 63;
  int nodeA = (blockIdx.x * 4 + (threadIdx.x >> 6)) * 2;
  if (nodeA >= n) return;
  int nodeB = nodeA + 1;
  float ssum = 0.f, qsum = 0.f;
#pragma unroll
  for (int k = 0; k < 8; ++k) {
    ssum += sums[k * 128 + lane];
    qsum += sums[k * 128 + 64 + lane];
  }
  float mu = ssum * invN;
  float var = qsum * invN - mu * mu;
  float aa = rsqrtf(var + 1e-5f) * bn_g[lane];
  float cc = bn_b[lane] - mu * aa;
  h2f16 wc2[4];
#pragma unroll
  for (int k = 0; k < 4; ++k) {
    H2U u;
    u.u = pack2h(edge_W[(2 * k) * 64 + lane], edge_W[(2 * k + 1) * 64 + lane]);
    wc2[k] = u.h;
  }
  float eb = edge_b[lane];
  float tt2 = t[0] * 1.44269504088896f;
  const char* hB = (const char*)h;
  const unsigned lane2 = (unsigned)lane * 2u;
  float resA = agg_one(nodeA, lane2, hB, rowstart, recs, wc2, eb, tt2, aa, cc);
  *(unsigned short*)((char*)out + ((unsigned)nodeA * 128u + lane2)) =
      __half_as_ushort(__float2half(resA));
  if (nodeB < n) {
    float resB = agg_one(nodeB, lane2, hB, rowstart, recs, wc2, eb, tt2, aa, cc);
    *(unsigned short*)((char*)out + ((unsigned)nodeB * 128u + lane2)) =
        __half_as_ushort(__float2half(resB));
  }
}

// MFMA MLP on f16 streams (unchanged from R14).
__global__ __launch_bounds__(256) void mlp_mfma_kernel(
    const unsigned short* __restrict__ outv, const unsigned short* __restrict__ h_in,
    const float* __restrict__ W1, const float* __restrict__ b1,
    const float* __restrict__ lng, const float* __restrict__ lnb,
    const float* __restrict__ W2, const float* __restrict__ b2,
    unsigned short* __restrict__ hout16, float* __restrict__ hout32,
    float* __restrict__ nextsums, int n) {
  __shared__ uint4 lds[2560];  // 40KB
  const int tid = threadIdx.x;
  const int wv = tid >> 6, l = tid & 63;
  const int n0 = blockIdx.x * 64;
  uint4* XA = lds;
  uint4* WB = lds + 512;
  uint4* ZF = lds + 1536;
#pragma unroll
  for (int i = 0; i < 2; ++i) {
    int c = tid + i * 256;
    int node = c >> 3, k8 = c & 7;
    int nd = n0 + node;
    uint4 u;
    if (nd < n) {
      u = *(const uint4*)(outv + (size_t)nd * 64 + k8 * 8);
    } else {
      u = make_uint4(0, 0, 0, 0);
    }
    int mt = node >> 4, kt = k8 >> 2;
    int lanep = ((k8 & 3) << 4) | (node & 15);
    XA[(mt * 2 + kt) * 64 + lanep] = u;
  }
#pragma unroll
  for (int i = 0; i < 4; ++i) {
    int c = tid + i * 256;
    int fid = c >> 6, lp = c & 63;
    int nt = fid >> 1, kt = fid & 1;
    int ncol = (nt << 4) | (lp & 15);
    int k0 = kt * 32 + (lp >> 4) * 8;
    half8 hv;
#pragma unroll
    for (int j = 0; j < 8; ++j) hv[j] = (_Float16)W1[(size_t)(k0 + j) * 128 + ncol];
    H8U u; u.h = hv;
    WB[fid * 64 + lp] = u.u;
  }
  __syncthreads();
  f32x4 cfr[8];
#pragma unroll
  for (int nt = 0; nt < 8; ++nt) cfr[nt] = (f32x4){0.f, 0.f, 0.f, 0.f};
  {
    H8U a0, a1;
    a0.u = XA[(wv * 2 + 0) * 64 + l];
    a1.u = XA[(wv * 2 + 1) * 64 + l];
#pragma unroll
    for (int nt = 0; nt < 8; ++nt) {
      H8U b0, b1u;
      b0.u = WB[(nt * 2 + 0) * 64 + l];
      b1u.u = WB[(nt * 2 + 1) * 64 + l];
      cfr[nt] = __builtin_amdgcn_mfma_f32_16x16x32_f16(a0.h, b0.h, cfr[nt], 0, 0, 0);
      cfr[nt] = __builtin_amdgcn_mfma_f32_16x16x32_f16(a1.h, b1u.h, cfr[nt], 0, 0, 0);
    }
  }
  int col = l & 15;
  float s4[4] = {0.f, 0.f, 0.f, 0.f}, q4[4] = {0.f, 0.f, 0.f, 0.f};
#pragma unroll
  for (int nt = 0; nt < 8; ++nt) {
    float bb = b1[nt * 16 + col];
#pragma unroll
    for (int r = 0; r < 4; ++r) {
      float v = cfr[nt][r] + bb;
      cfr[nt][r] = v;
      s4[r] += v;
      q4[r] = fmaf(v, v, q4[r]);
    }
  }
#pragma unroll
  for (int off = 1; off < 16; off <<= 1) {
#pragma unroll
    for (int r = 0; r < 4; ++r) {
      s4[r] += __shfl_xor(s4[r], off, 64);
      q4[r] += __shfl_xor(q4[r], off, 64);
    }
  }
  float mu4[4], rs4[4];
#pragma unroll
  for (int r = 0; r < 4; ++r) {
    float mu = s4[r] * (1.f / 128.f);
    float var = q4[r] * (1.f / 128.f) - mu * mu;
    mu4[r] = mu;
    rs4[r] = rsqrtf(var + 1e-5f);
  }
  {
    unsigned short* ZB = (unsigned short*)ZF;
#pragma unroll
    for (int nt = 0; nt < 8; ++nt) {
      int ch = nt * 16 + col;
      int kt2 = ch >> 5, kl = ch & 31;
      float g = lng[ch], bb = lnb[ch];
#pragma unroll
      for (int r = 0; r < 4; ++r) {
        int row = (l >> 4) * 4 + r;
        float zv = fmaxf((cfr[nt][r] - mu4[r]) * rs4[r] * g + bb, 0.f);
        int lanep = ((kl >> 3) << 4) | row;
        ZB[((wv * 4 + kt2) * 64 + lanep) * 8 + (kl & 7)] = __half_as_ushort(__float2half(zv));
      }
    }
  }
  __syncthreads();
#pragma unroll
  for (int i = 0; i < 4; ++i) {
    int c = tid + i * 256;
    int fid = c >> 6, lp = c & 63;
    int nt2 = fid >> 2, kt2 = fid & 3;
    int ncol = (nt2 << 4) | (lp & 15);
    int k0 = kt2 * 32 + (lp >> 4) * 8;
    half8 hv;
#pragma unroll
    for (int j = 0; j < 8; ++j) hv[j] = (_Float16)W2[(size_t)(k0 + j) * 64 + ncol];
    H8U u; u.h = hv;
    WB[fid * 64 + lp] = u.u;
  }
  __syncthreads();
  f32x4 dfr[4];
#pragma unroll
  for (int nt2 = 0; nt2 < 4; ++nt2) dfr[nt2] = (f32x4){0.f, 0.f, 0.f, 0.f};
  {
    H8U za[4];
#pragma unroll
    for (int kt2 = 0; kt2 < 4; ++kt2) za[kt2].u = ZF[(wv * 4 + kt2) * 64 + l];
#pragma unroll
    for (int nt2 = 0; nt2 < 4; ++nt2) {
#pragma unroll
      for (int kt2 = 0; kt2 < 4; ++kt2) {
        H8U bu;
        bu.u = WB[(nt2 * 4 + kt2) * 64 + l];
        dfr[nt2] = __builtin_amdgcn_mfma_f32_16x16x32_f16(za[kt2].h, bu.h, dfr[nt2], 0, 0, 0);
      }
    }
  }
  float ssum[4] = {0.f, 0.f, 0.f, 0.f}, qsum[4] = {0.f, 0.f, 0.f, 0.f};
#pragma unroll
  for (int nt2 = 0; nt2 < 4; ++nt2) {
    int ch2 = nt2 * 16 + col;
    float bb = b2[ch2];
#pragma unroll
    for (int r = 0; r < 4; ++r) {
      int nd = n0 + wv * 16 + (l >> 4) * 4 + r;
      if (nd < n) {
        float hv = __half2float(__ushort_as_half(h_in[(size_t)nd * 64 + ch2]));
        float v = hv + dfr[nt2][r] + bb;
        if (hout32 != nullptr) {
          hout32[(size_t)nd * 64 + ch2] = v;
        } else {
          hout16[(size_t)nd * 64 + ch2] = __half_as_ushort(__float2half(v));
        }
        ssum[nt2] += v;
        qsum[nt2] = fmaf(v, v, qsum[nt2]);
      }
    }
  }
  if (nextsums != nullptr) {
#pragma unroll
    for (int nt2 = 0; nt2 < 4; ++nt2) {
      ssum[nt2] += __shfl_xor(ssum[nt2], 16, 64);
      ssum[nt2] += __shfl_xor(ssum[nt2], 32, 64);
      qsum[nt2] += __shfl_xor(qsum[nt2], 16, 64);
      qsum[nt2] += __shfl_xor(qsum[nt2], 32, 64);
    }
    float* SS = (float*)(ZF + wv * 256);
    if (l < 16) {
#pragma unroll
      for (int nt2 = 0; nt2 < 4; ++nt2) {
        SS[nt2 * 16 + l] = ssum[nt2];
        SS[64 + nt2 * 16 + l] = qsum[nt2];
      }
    }
    __syncthreads();
    if (tid < 64) {
      float S = 0.f, Q = 0.f;
#pragma unroll
      for (int w = 0; w < 4; ++w) {
        const float* P = (const float*)(ZF + w * 256);
        S += P[tid];
        Q += P[64 + tid];
      }
      int slot = blockIdx.x & 7;
      atomicAdd(&nextsums[slot * 128 + tid], S);
      atomicAdd(&nextsums[slot * 128 + 64 + tid], Q);
    }
  }
}

extern "C" void kernel_launch(void* const* d_in, const int* in_sizes, int n_in,
                              void* d_out, int out_size, void* d_ws, size_t ws_size,
                              hipStream_t stream) {
  const float* x = (const float*)d_in[0];
  const int* edge_index = (const int*)d_in[1];
  const float* edge_attr = (const float*)d_in[2];
  const float* node_W = (const float*)d_in[3];
  const float* node_b = (const float*)d_in[4];
  const float* edge_W = (const float*)d_in[5];
  const float* edge_b = (const float*)d_in[6];
  const float* bn_g = (const float*)d_in[7];
  const float* bn_b = (const float*)d_in[8];
  const float* t = (const float*)d_in[9];
  const float* W1 = (const float*)d_in[10];
  const float* b1 = (const float*)d_in[11];
  const float* ln_g = (const float*)d_in[12];
  const float* ln_b = (const float*)d_in[13];
  const float* W2 = (const float*)d_in[14];
  const float* b2 = (const float*)d_in[15];

  int N = in_sizes[0] / HDIM;
  int E = in_sizes[1] / 2;
  const int* srcp = edge_index;
  const int* dstp = edge_index + E;

  char* ws = (char*)d_ws;
  size_t off = 0;
  auto alloc = [&](size_t bytes) {
    char* p = ws + off;
    off = (off + bytes + 255) & ~(size_t)255;
    return p;
  };
  // bnsums followed immediately by deg -> single memset covers both
  float* bnsums = (float*)alloc(3 * 1024 * 4);   // 12288 B (256-aligned)
  int* deg = (int*)alloc((size_t)N * 4);
  int* rowstart = (int*)alloc(((size_t)N + 1) * 4);
  int* idxw = (int*)alloc((size_t)E * 4);
  int* partials = (int*)alloc(1024 * 4);
  char* recs = (char*)alloc((size_t)E * 32);
  unsigned short* h = (unsigned short*)alloc((size_t)N * 64 * 2);
  unsigned short* outv = (unsigned short*)alloc((size_t)N * 64 * 2);
  (void)ws_size; (void)n_in; (void)out_size;

  int nb = (N + 255) / 256;  // 196 <= 256 (required by scan_fill's in-block top scan)
  hipMemsetAsync(bnsums, 0, 3 * 1024 * 4 + (size_t)N * 4, stream);
  init_h_stats_kernel<<<512, 256, 0, stream>>>(x, node_W, node_b, h, bnsums,
                                               dstp, idxw, deg, N, E);
  scan_part_kernel<<<nb, 256, 0, stream>>>(deg, partials, N);
  scan_fill_kernel<<<nb, 256, 0, stream>>>(deg, partials, rowstart, N, E, nb);
  fill_kernel<<<(E + 255) / 256, 256, 0, stream>>>(srcp, dstp, idxw, rowstart, edge_attr, recs, E);

  float invN = 1.0f / (float)N;
  int mlp_blocks = (N + 63) / 64;
  int agg_blocks = (N + 7) / 8;  // 4 waves/block, 2 nodes/wave
  for (int l = 0; l < 3; ++l) {
    aggregate_kernel<<<agg_blocks, 256, 0, stream>>>(
        h, bnsums + l * 1024, bn_g + l * 64, bn_b + l * 64, rowstart, recs,
        edge_W, edge_b, t + l, outv, N, invN);
    unsigned short* h16 = (l == 2) ? nullptr : h;
    float* h32 = (l == 2) ? (float*)d_out : nullptr;
    float* nxt = (l == 2) ? nullptr : (bnsums + (l + 1) * 1024);
    mlp_mfma_kernel<<<mlp_blocks, 256, 0, stream>>>(outv, h, W1 + (size_t)l * 8192, b1 + l * 128,
                                                    ln_g + l * 128, ln_b + l * 128,
                                                    W2 + (size_t)l * 8192, b2 + l * 64,
                                                    h16, h32, nxt, N);
  }
}